// Round 1
// baseline (897.492 us; speedup 1.0000x reference)
//
#include <hip/hip_runtime.h>

// RNN scan: B=2048, T=512, V=64, H=256, K=H+V=320.
// R3: 128 blocks x 512 threads (8 waves, 2 waves/SIMD). Each block owns 16
// batch rows for all 512 steps; each wave owns 32 output columns (2 N-tiles).
// Rationale: R2 ran 1 wave/SIMD (Occupancy 5.8%) -> every latency in the
// step-critical path (MFMA chain, DPP tree, LDS round-trips, barriers) was
// fully exposed (~2000 of ~2960 cy/step). Two waves/SIMD interleave two
// independent instruction streams over the same latencies.
// Theta lives in VGPRs as MFMA B-fragments (bfrag[10][2], 80 VGPR).
// State double-buffered in LDS as bf16. Tokens stream global->VGPR in A-frag
// layout, prefetched one step ahead; raw s_barrier with lgkmcnt-only drain
// keeps the prefetch in flight across barriers.

#define TT 512
#define VV 64
#define HH 256
#define STRD 264   // ushorts per state row: 256 + 8 pad (33 x 16B -> ~2-way max on b128)
#define PSTRD 10   // float2 per partials row: 8 waves + 2 pad (80B stride, 16B-aligned)

typedef short bf16x8 __attribute__((ext_vector_type(8)));
typedef float f32x4  __attribute__((ext_vector_type(4)));

__device__ __forceinline__ unsigned short f2bf(float f) {
    unsigned int u = __float_as_uint(f);
    return (unsigned short)((u + 0x8000u) >> 16);   // round-to-nearest (no tie fix)
}

__device__ __forceinline__ float bf2f(unsigned short u) {
    return __uint_as_float(((unsigned int)u) << 16);
}

__device__ __forceinline__ bf16x8 pack8(float4 a, float4 b) {
    bf16x8 v;
    v[0] = (short)f2bf(a.x); v[1] = (short)f2bf(a.y);
    v[2] = (short)f2bf(a.z); v[3] = (short)f2bf(a.w);
    v[4] = (short)f2bf(b.x); v[5] = (short)f2bf(b.y);
    v[6] = (short)f2bf(b.z); v[7] = (short)f2bf(b.w);
    return v;
}

// x += dpp_perm(x); CTRL compile-time. VALU pipe (keeps LDS pipe free).
template <int CTRL>
__device__ __forceinline__ float dppadd(float x) {
    int y = __builtin_amdgcn_update_dpp(0, __float_as_int(x), CTRL, 0xF, 0xF, false);
    return x + __int_as_float(y);
}

// quad_perm broadcast: lanes 4a..4a+3 <- lane 4a + r (CTRL = rrrr pattern)
template <int CTRL>
__device__ __forceinline__ float dppbcast(float x) {
    int y = __builtin_amdgcn_update_dpp(0, __float_as_int(x), CTRL, 0xF, 0xF, true);
    return __int_as_float(y);
}

// s_barrier with LDS-only drain: do NOT drain vmcnt (keeps token prefetch in
// flight across the barrier). LDS visibility needs lgkmcnt(0) only.
__device__ __forceinline__ void barrier_lgkm() {
    asm volatile("s_waitcnt lgkmcnt(0)\n\ts_barrier" ::: "memory");
}

extern "C" __global__ void __launch_bounds__(512, 2)
rnn_scan_kernel(const float* __restrict__ seq,        // [2048][512][64]
                const float* __restrict__ theta,      // [256][320]
                const float* __restrict__ theta_dot,  // [256]
                float* __restrict__ out)              // [2048]
{
    __shared__ unsigned short stbuf[2][16][STRD];            // state, bf16, double-buffered
    __shared__ __align__(16) float2 partials[16 * PSTRD];    // [row][wave 0..7] (sum, sumsq)

    const int tid = threadIdx.x;
    const int w   = tid >> 6;        // wave 0..7  -> N columns [32w, 32w+32)
    const int l   = tid & 63;        // lane
    const int q   = l >> 4;          // quad-row group 0..3
    const int loc = l & 15;
    const int r0  = blockIdx.x << 4; // first batch row of this block

    // ---- Theta -> resident B-fragments: bfrag[ks][s] covers K [32ks,32ks+32) x N [32w+16s, +16)
    bf16x8 bfrag[10][2];
#pragma unroll
    for (int s = 0; s < 2; ++s) {
        const float* trow = theta + (size_t)(w * 32 + s * 16 + loc) * 320;
#pragma unroll
        for (int ks = 0; ks < 10; ++ks) {
            float4 f0 = *(const float4*)(trow + ks * 32 + q * 8);
            float4 f1 = *(const float4*)(trow + ks * 32 + q * 8 + 4);
            bfrag[ks][s] = pack8(f0, f1);
        }
    }

    // ---- zero initial state (buffer 0) ----
    if (tid < 256) {
        const int m = tid >> 4, c = (tid & 15) * 16;
        uint4 z = make_uint4(0u, 0u, 0u, 0u);
        *(uint4*)(&stbuf[0][m][c])     = z;
        *(uint4*)(&stbuf[0][m][c + 8]) = z;
    }

    // ---- prefetch token t=0 in A-frag layout: lane = row loc, features q*8.. ----
    const float* srow = seq + (size_t)(r0 + loc) * (TT * VV);
    float4 tk0 = *(const float4*)(srow + q * 8);
    float4 tk1 = *(const float4*)(srow + q * 8 + 4);
    float4 tk2 = *(const float4*)(srow + 32 + q * 8);
    float4 tk3 = *(const float4*)(srow + 32 + q * 8 + 4);

    __syncthreads();

#pragma unroll 1
    for (int t = 0; t < TT; ++t) {
        unsigned short* stc = &stbuf[t & 1][0][0];
        unsigned short* stn = &stbuf[(t + 1) & 1][0][0];

        // token A-frags for this step (K blocks 8,9 = features 0..31 / 32..63)
        bf16x8 a8 = pack8(tk0, tk1);
        bf16x8 a9 = pack8(tk2, tk3);

        // prefetch next step's token; with raw barriers this stays in flight
        // until the pack8 at the top of the next iteration (full-step cover)
        if (t + 1 < TT) {
            const float* p = srow + (size_t)(t + 1) * VV;
            tk0 = *(const float4*)(p + q * 8);
            tk1 = *(const float4*)(p + q * 8 + 4);
            tk2 = *(const float4*)(p + 32 + q * 8);
            tk3 = *(const float4*)(p + 32 + q * 8 + 4);
        }

        // ---- GEMM phase: z[16 x 32w..] = [state|token] . theta^T ----
        f32x4 acc[2];
#pragma unroll
        for (int s = 0; s < 2; ++s) { acc[s][0] = 0.f; acc[s][1] = 0.f; acc[s][2] = 0.f; acc[s][3] = 0.f; }

        const unsigned short* arow = stc + loc * STRD;   // A-frag: lane = row loc
#pragma unroll
        for (int ks = 0; ks < 8; ++ks) {
            bf16x8 av = *(const bf16x8*)(arow + ks * 32 + q * 8);  // ds_read_b128
#pragma unroll
            for (int s = 0; s < 2; ++s)
                acc[s] = __builtin_amdgcn_mfma_f32_16x16x32_bf16(av, bfrag[ks][s], acc[s], 0, 0, 0);
        }
#pragma unroll
        for (int s = 0; s < 2; ++s)
            acc[s] = __builtin_amdgcn_mfma_f32_16x16x32_bf16(a8, bfrag[8][s], acc[s], 0, 0, 0);
#pragma unroll
        for (int s = 0; s < 2; ++s)
            acc[s] = __builtin_amdgcn_mfma_f32_16x16x32_bf16(a9, bfrag[9][s], acc[s], 0, 0, 0);

        // ---- per-row partial stats over this wave's 32 columns ----
        // C layout: acc[s][r] is row q*4+r, col w*32 + s*16 + loc
        float sum[4], ssq[4];
#pragma unroll
        for (int r = 0; r < 4; ++r) {
            sum[r] = acc[0][r] + acc[1][r];
            ssq[r] = acc[0][r] * acc[0][r] + acc[1][r] * acc[1][r];
        }
        // reduce across 16 lanes of the quad-row group: xor1, xor2, ror4, ror8 (DPP)
#pragma unroll
        for (int r = 0; r < 4; ++r) {
            sum[r] = dppadd<0xB1>(sum[r]);  ssq[r] = dppadd<0xB1>(ssq[r]);   // quad_perm 1,0,3,2
            sum[r] = dppadd<0x4E>(sum[r]);  ssq[r] = dppadd<0x4E>(ssq[r]);   // quad_perm 2,3,0,1
            sum[r] = dppadd<0x124>(sum[r]); ssq[r] = dppadd<0x124>(ssq[r]);  // row_ror:4
            sum[r] = dppadd<0x128>(sum[r]); ssq[r] = dppadd<0x128>(ssq[r]);  // row_ror:8
        }
        if (loc < 4)
            partials[(q * 4 + loc) * PSTRD + w] = make_float2(sum[loc], ssq[loc]);

        barrier_lgkm();

        // ---- finalize stats: lane handles row q*4+(loc&3); 4 lanes redundant ----
        // partials[row][0..7] = 64B contiguous (80B row stride) -> four b128 broadcast reads
        const int myrow = (q << 2) | (loc & 3);
        const float2* pr = &partials[myrow * PSTRD];
        float4 pA = *(const float4*)(pr + 0); // waves 0,1
        float4 pB = *(const float4*)(pr + 2); // waves 2,3
        float4 pC = *(const float4*)(pr + 4); // waves 4,5
        float4 pD = *(const float4*)(pr + 6); // waves 6,7
        float sumT = ((pA.x + pA.z) + (pB.x + pB.z)) + ((pC.x + pC.z) + (pD.x + pD.z));
        float ssqT = ((pA.y + pA.w) + (pB.y + pB.w)) + ((pC.y + pC.w) + (pD.y + pD.w));
        float mean = sumT * (1.0f / 256.0f);
        float var  = (ssqT - sumT * mean) * (1.0f / 255.0f);   // ddof=1 (Bessel)
        float rstd = rsqrtf(var);
        float nb   = -mean * rstd;                              // v = fma(z, rstd, nb)

        // broadcast (rstd, nb) for rows q*4+r to all lanes of each nibble (VALU DPP)
        float rs[4], nbv[4];
        rs[0] = dppbcast<0x00>(rstd); nbv[0] = dppbcast<0x00>(nb);
        rs[1] = dppbcast<0x55>(rstd); nbv[1] = dppbcast<0x55>(nb);
        rs[2] = dppbcast<0xAA>(rstd); nbv[2] = dppbcast<0xAA>(nb);
        rs[3] = dppbcast<0xFF>(rstd); nbv[3] = dppbcast<0xFF>(nb);

        // ---- normalize, relu, write next-state bf16 ----
#pragma unroll
        for (int s = 0; s < 2; ++s) {
#pragma unroll
            for (int r = 0; r < 4; ++r) {
                float v = fmaf(acc[s][r], rs[r], nbv[r]);
                v = fmaxf(v, 0.0f);
                stn[(q * 4 + r) * STRD + (w * 32 + s * 16 + loc)] = f2bf(v);
            }
        }
        barrier_lgkm();
    }

    // ---- readout: logits = state . theta_dot ; out = sigmoid(logits) ----
    // final state is in buffer (T & 1) ^ 1 == 0
    if (tid < 256) {
        const int m = tid >> 4, c0 = (tid & 15) << 4;
        const unsigned short* sr = &stbuf[0][m][c0];
        float dot = 0.0f;
#pragma unroll
        for (int j = 0; j < 16; ++j)
            dot += bf2f(sr[j]) * theta_dot[c0 + j];
        dot += __shfl_xor(dot, 1, 64);
        dot += __shfl_xor(dot, 2, 64);
        dot += __shfl_xor(dot, 4, 64);
        dot += __shfl_xor(dot, 8, 64);
        if ((tid & 15) == 0)
            out[r0 + m] = 1.0f / (1.0f + expf(-dot));
    }
}

extern "C" void kernel_launch(void* const* d_in, const int* in_sizes, int n_in,
                              void* d_out, int out_size, void* d_ws, size_t ws_size,
                              hipStream_t stream) {
    const float* seq   = (const float*)d_in[0];  // [2048*512*64]
    const float* theta = (const float*)d_in[1];  // [256*320]
    // d_in[2] = bias[1]: constant shift cancels exactly in LayerNorm -> unused
    const float* tdot  = (const float*)d_in[3];  // [256]
    float* out = (float*)d_out;

    rnn_scan_kernel<<<dim3(128), dim3(512), 0, stream>>>(seq, theta, tdot, out);
}

// Round 2
// 879.983 us; speedup vs baseline: 1.0199x; 1.0199x over previous
//
#include <hip/hip_runtime.h>

// RNN scan: B=2048, T=512, V=64, H=256, K=H+V=320.
// R4: 256 blocks x 256 threads (4 waves), 8 REAL batch rows per block (MFMA
// rows 8..15 are junk mirrors, contained: all math is row-local). 2 independent
// blocks co-reside per CU (__launch_bounds__(256,2)) -> block A's barrier
// stalls are hidden by block B's work (R3 showed same-block waves stall
// together; independent barrier groups are the TLP that works).
// Defer-rstd: relu((z-u)/s) = (1/s)*relu(z-u); state stored UNSCALED, rstd
// folded into next step's merge (z = rstd_prev*acc_state + acc_token). Mean is
// the only stat on the critical path; var/rsqrt/its broadcasts are shadowed.
// Token MFMAs (K-blocks 8,9: register-only) computed in the stats window for
// step t+1, filling the partials-read latency.
// Theta resident in VGPRs (bfrag[10][4]); state double-buffered bf16 in LDS;
// raw s_barrier with lgkmcnt-only drain keeps token prefetch in flight.

#define TT 512
#define VV 64
#define STRD 264   // ushorts per state row: 256 + 8 pad

typedef short bf16x8 __attribute__((ext_vector_type(8)));
typedef float f32x4  __attribute__((ext_vector_type(4)));

__device__ __forceinline__ unsigned short f2bf(float f) {
    unsigned int u = __float_as_uint(f);
    return (unsigned short)((u + 0x8000u) >> 16);   // round-to-nearest
}

__device__ __forceinline__ float bf2f(unsigned short u) {
    return __uint_as_float(((unsigned int)u) << 16);
}

__device__ __forceinline__ bf16x8 pack8(float4 a, float4 b) {
    bf16x8 v;
    v[0] = (short)f2bf(a.x); v[1] = (short)f2bf(a.y);
    v[2] = (short)f2bf(a.z); v[3] = (short)f2bf(a.w);
    v[4] = (short)f2bf(b.x); v[5] = (short)f2bf(b.y);
    v[6] = (short)f2bf(b.z); v[7] = (short)f2bf(b.w);
    return v;
}

template <int CTRL>
__device__ __forceinline__ float dppadd(float x) {
    int y = __builtin_amdgcn_update_dpp(0, __float_as_int(x), CTRL, 0xF, 0xF, false);
    return x + __int_as_float(y);
}

template <int CTRL>
__device__ __forceinline__ float dppbcast(float x) {
    int y = __builtin_amdgcn_update_dpp(0, __float_as_int(x), CTRL, 0xF, 0xF, true);
    return __int_as_float(y);
}

__device__ __forceinline__ void barrier_lgkm() {
    asm volatile("s_waitcnt lgkmcnt(0)\n\ts_barrier" ::: "memory");
}

extern "C" __global__ void __launch_bounds__(256, 2)
rnn_scan_kernel(const float* __restrict__ seq,        // [2048][512][64]
                const float* __restrict__ theta,      // [256][320]
                const float* __restrict__ theta_dot,  // [256]
                float* __restrict__ out)              // [2048]
{
    __shared__ unsigned short stbuf[2][16][STRD];        // state U, bf16, dbuf
    __shared__ __align__(16) float2 partials[64];        // [row 0..15][wave 0..3]
    __shared__ float rstd_lds[16];

    const int tid = threadIdx.x;
    const int w   = tid >> 6;        // wave 0..3 -> N columns [64w, 64w+64)
    const int l   = tid & 63;
    const int q   = l >> 4;          // quad-row group 0..3
    const int loc = l & 15;
    const int r0  = blockIdx.x << 3; // first REAL batch row (8 per block)

    // ---- Theta -> resident B-fragments ----
    bf16x8 bfrag[10][4];
#pragma unroll
    for (int s = 0; s < 4; ++s) {
        const float* trow = theta + (size_t)(w * 64 + s * 16 + loc) * 320;
#pragma unroll
        for (int ks = 0; ks < 10; ++ks) {
            float4 f0 = *(const float4*)(trow + ks * 32 + q * 8);
            float4 f1 = *(const float4*)(trow + ks * 32 + q * 8 + 4);
            bfrag[ks][s] = pack8(f0, f1);
        }
    }

    // ---- zero BOTH state buffers (junk rows 8..15 stay frozen-finite) ----
    {
        const int m = tid >> 4, c = (tid & 15) * 16;
        uint4 z = make_uint4(0u, 0u, 0u, 0u);
        *(uint4*)(&stbuf[0][m][c])     = z;
        *(uint4*)(&stbuf[0][m][c + 8]) = z;
        *(uint4*)(&stbuf[1][m][c])     = z;
        *(uint4*)(&stbuf[1][m][c + 8]) = z;
    }

    // ---- tokens: lane row = r0 + (loc & 7); junk lanes mirror real rows
    // (same cachelines, no extra HBM) ----
    const float* srow = seq + (size_t)(r0 + (loc & 7)) * (TT * VV);
    float4 tk0 = *(const float4*)(srow + q * 8);
    float4 tk1 = *(const float4*)(srow + q * 8 + 4);
    float4 tk2 = *(const float4*)(srow + 32 + q * 8);
    float4 tk3 = *(const float4*)(srow + 32 + q * 8 + 4);

    // token part of step 0 (register-only MFMAs)
    f32x4 acc_t[4];
    {
        bf16x8 a8 = pack8(tk0, tk1);
        bf16x8 a9 = pack8(tk2, tk3);
        f32x4 zc; zc[0] = 0.f; zc[1] = 0.f; zc[2] = 0.f; zc[3] = 0.f;
#pragma unroll
        for (int s = 0; s < 4; ++s) {
            acc_t[s] = __builtin_amdgcn_mfma_f32_16x16x32_bf16(a8, bfrag[8][s], zc, 0, 0, 0);
            acc_t[s] = __builtin_amdgcn_mfma_f32_16x16x32_bf16(a9, bfrag[9][s], acc_t[s], 0, 0, 0);
        }
    }
    // prefetch t=1
    {
        const float* p = srow + VV;
        tk0 = *(const float4*)(p + q * 8);
        tk1 = *(const float4*)(p + q * 8 + 4);
        tk2 = *(const float4*)(p + 32 + q * 8);
        tk3 = *(const float4*)(p + 32 + q * 8 + 4);
    }

    float rs[4];
    rs[0] = 1.0f; rs[1] = 1.0f; rs[2] = 1.0f; rs[3] = 1.0f;   // state==0 at t=0

    __syncthreads();

#pragma unroll 1
    for (int t = 0; t < TT; ++t) {
        unsigned short* stc = &stbuf[t & 1][0][0];
        unsigned short* stn = &stbuf[(t + 1) & 1][0][0];

        // ---- GEMM state part: acc = U(t) . theta_state^T ----
        f32x4 acc[4];
#pragma unroll
        for (int s = 0; s < 4; ++s) { acc[s][0] = 0.f; acc[s][1] = 0.f; acc[s][2] = 0.f; acc[s][3] = 0.f; }

        const unsigned short* arow = stc + loc * STRD;
#pragma unroll
        for (int ks = 0; ks < 8; ++ks) {
            bf16x8 av = *(const bf16x8*)(arow + ks * 32 + q * 8);  // ds_read_b128
#pragma unroll
            for (int s = 0; s < 4; ++s)
                acc[s] = __builtin_amdgcn_mfma_f32_16x16x32_bf16(av, bfrag[ks][s], acc[s], 0, 0, 0);
        }

        // ---- merge: z = rstd(t-1) * acc_state + acc_token ----
#pragma unroll
        for (int s = 0; s < 4; ++s)
#pragma unroll
            for (int r = 0; r < 4; ++r)
                acc[s][r] = fmaf(acc[s][r], rs[r], acc_t[s][r]);

        // ---- per-row partial stats over this wave's 64 columns ----
        float sum[4], ssq[4];
#pragma unroll
        for (int r = 0; r < 4; ++r) {
            sum[r] = acc[0][r] + acc[1][r] + acc[2][r] + acc[3][r];
            ssq[r] = acc[0][r] * acc[0][r] + acc[1][r] * acc[1][r]
                   + acc[2][r] * acc[2][r] + acc[3][r] * acc[3][r];
        }
#pragma unroll
        for (int r = 0; r < 4; ++r) {
            sum[r] = dppadd<0xB1>(sum[r]);  ssq[r] = dppadd<0xB1>(ssq[r]);
            sum[r] = dppadd<0x4E>(sum[r]);  ssq[r] = dppadd<0x4E>(ssq[r]);
            sum[r] = dppadd<0x124>(sum[r]); ssq[r] = dppadd<0x124>(ssq[r]);
            sum[r] = dppadd<0x128>(sum[r]); ssq[r] = dppadd<0x128>(ssq[r]);
        }
        if (loc < 4)
            partials[((q * 4 + loc) << 2) | w] = make_float2(sum[loc], ssq[loc]);

        barrier_lgkm();

        // ---- stats window: issue partials reads, then register-only work ----
        const int myrow = (q << 2) | (loc & 3);
        float4 pA = *(const float4*)(&partials[myrow << 2]);       // waves 0,1
        float4 pB = *(const float4*)(&partials[(myrow << 2) | 2]); // waves 2,3

        // token part for t+1 (fills partials-read latency; register-only)
        if (t + 1 < TT) {
            bf16x8 a8 = pack8(tk0, tk1);
            bf16x8 a9 = pack8(tk2, tk3);
            f32x4 zc; zc[0] = 0.f; zc[1] = 0.f; zc[2] = 0.f; zc[3] = 0.f;
#pragma unroll
            for (int s = 0; s < 4; ++s) {
                acc_t[s] = __builtin_amdgcn_mfma_f32_16x16x32_bf16(a8, bfrag[8][s], zc, 0, 0, 0);
                acc_t[s] = __builtin_amdgcn_mfma_f32_16x16x32_bf16(a9, bfrag[9][s], acc_t[s], 0, 0, 0);
            }
            if (t + 2 < TT) {
                const float* p = srow + (size_t)(t + 2) * VV;
                tk0 = *(const float4*)(p + q * 8);
                tk1 = *(const float4*)(p + q * 8 + 4);
                tk2 = *(const float4*)(p + 32 + q * 8);
                tk3 = *(const float4*)(p + 32 + q * 8 + 4);
            }
        }

        // ---- critical path: mean only ----
        float sumT = (pA.x + pA.z) + (pB.x + pB.z);
        float ssqT = (pA.y + pA.w) + (pB.y + pB.w);
        float mean = sumT * (1.0f / 256.0f);
        float nm   = -mean;
        float mb[4];
        mb[0] = dppbcast<0x00>(nm);
        mb[1] = dppbcast<0x55>(nm);
        mb[2] = dppbcast<0xAA>(nm);
        mb[3] = dppbcast<0xFF>(nm);

        // ---- write U(t+1) = relu(z - mean), UNSCALED, real rows only (q<2) ----
        if (q < 2) {
#pragma unroll
            for (int s = 0; s < 4; ++s)
#pragma unroll
                for (int r = 0; r < 4; ++r) {
                    float v = fmaxf(acc[s][r] + mb[r], 0.0f);
                    stn[(q * 4 + r) * STRD + (w * 64 + s * 16 + loc)] = f2bf(v);
                }
        }

        // ---- deferred: rstd(t) for next step's merge (off critical path) ----
        float var  = (ssqT - sumT * mean) * (1.0f / 255.0f);   // ddof=1
        float rstd = rsqrtf(var);
        rs[0] = dppbcast<0x00>(rstd);
        rs[1] = dppbcast<0x55>(rstd);
        rs[2] = dppbcast<0xAA>(rstd);
        rs[3] = dppbcast<0xFF>(rstd);

        barrier_lgkm();
    }

    // ---- publish final rstd for readout scale ----
    if (w == 0 && loc == 0) {
#pragma unroll
        for (int r = 0; r < 4; ++r)
            rstd_lds[q * 4 + r] = rs[r];
    }
    __syncthreads();

    // ---- readout: logits = rstd * (U . theta_dot); out = sigmoid ----
    {
        const int m = tid >> 4, c0 = (tid & 15) << 4;
        const unsigned short* sr = &stbuf[0][m][c0];
        float dot = 0.0f;
#pragma unroll
        for (int j = 0; j < 16; ++j)
            dot += bf2f(sr[j]) * theta_dot[c0 + j];
        dot += __shfl_xor(dot, 1, 64);
        dot += __shfl_xor(dot, 2, 64);
        dot += __shfl_xor(dot, 4, 64);
        dot += __shfl_xor(dot, 8, 64);
        if ((tid & 15) == 0 && m < 8)
            out[r0 + m] = 1.0f / (1.0f + expf(-rstd_lds[m] * dot));
    }
}

extern "C" void kernel_launch(void* const* d_in, const int* in_sizes, int n_in,
                              void* d_out, int out_size, void* d_ws, size_t ws_size,
                              hipStream_t stream) {
    const float* seq   = (const float*)d_in[0];  // [2048*512*64]
    const float* theta = (const float*)d_in[1];  // [256*320]
    // d_in[2] = bias[1]: constant shift cancels in LayerNorm -> unused
    const float* tdot  = (const float*)d_in[3];  // [256]
    float* out = (float*)d_out;

    rnn_scan_kernel<<<dim3(256), dim3(256), 0, stream>>>(seq, theta, tdot, out);
}